// Round 2
// baseline (3236.306 us; speedup 1.0000x reference)
//
#include <hip/hip_runtime.h>
#include <stdint.h>

#define N_NODES 100000
#define N_EDGES 600000
#define DIM_H   128
#define DIM_OUT 64
#define WPAD    136      // padded LDS row stride in ushort units (272B = 17*16B)
#define BN_EPS  1e-5f

typedef __attribute__((ext_vector_type(8))) __bf16        bh8;
typedef __attribute__((ext_vector_type(4))) float         fl4;
typedef __attribute__((ext_vector_type(8))) unsigned short us8;
typedef __attribute__((ext_vector_type(4))) unsigned short us4;

__device__ __forceinline__ unsigned short f2bfbits(float f) {
  unsigned int u = __builtin_bit_cast(unsigned int, f);
  u += 0x7fffu + ((u >> 16) & 1u);           // RNE
  return (unsigned short)(u >> 16);
}
__device__ __forceinline__ float bf2f(unsigned short b) {
  unsigned int u = ((unsigned int)b) << 16;
  return __builtin_bit_cast(float, u);
}

// ---------------- weight prep: transpose + bf16 cast, zero stats ----------------
__global__ void prep_kernel(const float* __restrict__ cw1, const float* __restrict__ cw2,
                            const float* __restrict__ fc1w, const float* __restrict__ fc2w,
                            unsigned short* __restrict__ W1T, unsigned short* __restrict__ W2T,
                            unsigned short* __restrict__ F1T, unsigned short* __restrict__ F2T,
                            float* __restrict__ stats) {
  int t = blockIdx.x * 256 + threadIdx.x;
  if (t < 3 * 16384) {
    int l = t / 16384, r = t % 16384;
    int nn = r >> 7, k = r & 127;            // W*T[l][n][k] = W[l][k][n]
    W1T[t] = f2bfbits(cw1[l * 16384 + k * 128 + nn]);
    W2T[t] = f2bfbits(cw2[l * 16384 + k * 128 + nn]);
  }
  if (t < 16384) { int nn = t >> 7, k = t & 127; F1T[t] = f2bfbits(fc1w[k * 128 + nn]); }
  if (t < 8192)  { int nn = t >> 7, k = t & 127; F2T[t] = f2bfbits(fc2w[k * 64 + nn]); }
  if (t < 768)   stats[t] = 0.f;
}

// ---------------- agg init ----------------
__global__ void agg_init_x(const float* __restrict__ x, float* __restrict__ agg) {
  int i = blockIdx.x * 256 + threadIdx.x;    // float4 index, grid exact
  reinterpret_cast<fl4*>(agg)[i] = reinterpret_cast<const fl4*>(x)[i];
}

__global__ void agg_init_z(const unsigned short* __restrict__ Z, const float* __restrict__ sb,
                           float* __restrict__ agg) {
  int t = blockIdx.x * 256 + threadIdx.x;    // chunk of 8 cols, grid exact
  int row = t >> 4, c8 = (t & 15) << 3;
  us8 zv = *reinterpret_cast<const us8*>(Z + (long)row * DIM_H + c8);
  fl4 o0, o1;
#pragma unroll
  for (int j = 0; j < 4; ++j) o0[j] = bf2f(zv[j])     * sb[c8 + j]     + sb[128 + c8 + j];
#pragma unroll
  for (int j = 0; j < 4; ++j) o1[j] = bf2f(zv[4 + j]) * sb[c8 + 4 + j] + sb[128 + c8 + 4 + j];
  *reinterpret_cast<fl4*>(agg + (long)row * DIM_H + c8)     = o0;
  *reinterpret_cast<fl4*>(agg + (long)row * DIM_H + c8 + 4) = o1;
}

// ---------------- edge scatter (32 lanes / edge, 4 floats / lane) ----------------
__global__ void scatter_x(const float* __restrict__ x, const int* __restrict__ ei,
                          float* __restrict__ agg) {
  int t = blockIdx.x * 256 + threadIdx.x;
  int e = t >> 5, c = (t & 31) << 2;
  if (e >= N_EDGES) return;
  int src = ei[e];
  int dst = ei[N_EDGES + e];
  fl4 v = *reinterpret_cast<const fl4*>(x + (long)src * DIM_H + c);
  float* p = agg + (long)dst * DIM_H + c;
  unsafeAtomicAdd(p + 0, v[0]); unsafeAtomicAdd(p + 1, v[1]);
  unsafeAtomicAdd(p + 2, v[2]); unsafeAtomicAdd(p + 3, v[3]);
}

__global__ void scatter_z(const unsigned short* __restrict__ Z, const float* __restrict__ sb,
                          const int* __restrict__ ei, float* __restrict__ agg) {
  int t = blockIdx.x * 256 + threadIdx.x;
  int e = t >> 5, c = (t & 31) << 2;
  if (e >= N_EDGES) return;
  int src = ei[e];
  int dst = ei[N_EDGES + e];
  us4 zv = *reinterpret_cast<const us4*>(Z + (long)src * DIM_H + c);
  fl4 s = *reinterpret_cast<const fl4*>(sb + c);
  fl4 b = *reinterpret_cast<const fl4*>(sb + 128 + c);
  float* p = agg + (long)dst * DIM_H + c;
  unsafeAtomicAdd(p + 0, bf2f(zv[0]) * s[0] + b[0]);
  unsafeAtomicAdd(p + 1, bf2f(zv[1]) * s[1] + b[1]);
  unsafeAtomicAdd(p + 2, bf2f(zv[2]) * s[2] + b[2]);
  unsafeAtomicAdd(p + 3, bf2f(zv[3]) * s[3] + b[3]);
}

// ---------------- fused GIN MLP: z = relu(relu(agg@W1+b1)@W2+b2), + BN stats ----------------
__global__ __launch_bounds__(256, 2)
void mlp_kernel(const float* __restrict__ A,
                const unsigned short* __restrict__ W1T, const float* __restrict__ b1,
                const unsigned short* __restrict__ W2T, const float* __restrict__ b2,
                unsigned short* __restrict__ Z, float* __restrict__ stats) {
  __shared__ __align__(16) unsigned short wbuf[128 * WPAD];
  __shared__ __align__(16) unsigned short ybuf[128 * WPAD];
  __shared__ float red[4][2][128];

  const int tid = threadIdx.x;
  const int wid = tid >> 6, lane = tid & 63;
  const int lr = lane & 15, lg = lane >> 4;
  const int row0 = blockIdx.x * 128;

  // stage W1T
#pragma unroll
  for (int i = 0; i < 8; ++i) {
    int chunk = tid + i * 256;
    int r = chunk >> 4, c8 = (chunk & 15) << 3;
    *reinterpret_cast<uint4*>(&wbuf[r * WPAD + c8]) =
        *reinterpret_cast<const uint4*>(&W1T[r * 128 + c8]);
  }

  // A fragments from global fp32, convert to bf16
  bh8 afrag[2][4];
#pragma unroll
  for (int rt = 0; rt < 2; ++rt) {
    int row = row0 + wid * 32 + rt * 16 + lr;
    bool valid = row < N_NODES;
    const float* ap = A + (long)row * DIM_H;
#pragma unroll
    for (int kk = 0; kk < 4; ++kk) {
      int k0 = kk * 32 + 8 * lg;
      us8 t = (us8)0;
      if (valid) {
        fl4 v0 = *reinterpret_cast<const fl4*>(ap + k0);
        fl4 v1 = *reinterpret_cast<const fl4*>(ap + k0 + 4);
#pragma unroll
        for (int j = 0; j < 4; ++j) { t[j] = f2bfbits(v0[j]); t[4 + j] = f2bfbits(v1[j]); }
      }
      afrag[rt][kk] = __builtin_bit_cast(bh8, t);
    }
  }

  __syncthreads();

  // GEMM1 + bias + relu -> ybuf (bf16)
#pragma unroll
  for (int n0 = 0; n0 < 8; ++n0) {
    fl4 acc[2] = {{0,0,0,0},{0,0,0,0}};
#pragma unroll
    for (int kk = 0; kk < 4; ++kk) {
      bh8 b = *reinterpret_cast<const bh8*>(&wbuf[(n0 * 16 + lr) * WPAD + kk * 32 + 8 * lg]);
      acc[0] = __builtin_amdgcn_mfma_f32_16x16x32_bf16(afrag[0][kk], b, acc[0], 0, 0, 0);
      acc[1] = __builtin_amdgcn_mfma_f32_16x16x32_bf16(afrag[1][kk], b, acc[1], 0, 0, 0);
    }
    float bias = b1[n0 * 16 + lr];
#pragma unroll
    for (int rt = 0; rt < 2; ++rt)
#pragma unroll
      for (int r = 0; r < 4; ++r) {
        float v = acc[rt][r] + bias;
        v = v > 0.f ? v : 0.f;
        ybuf[(wid * 32 + rt * 16 + 4 * lg + r) * WPAD + n0 * 16 + lr] = f2bfbits(v);
      }
  }

  __syncthreads();           // everyone done with W1T + Y1 writes

  // stage W2T over wbuf
#pragma unroll
  for (int i = 0; i < 8; ++i) {
    int chunk = tid + i * 256;
    int r = chunk >> 4, c8 = (chunk & 15) << 3;
    *reinterpret_cast<uint4*>(&wbuf[r * WPAD + c8]) =
        *reinterpret_cast<const uint4*>(&W2T[r * 128 + c8]);
  }

  // A2 fragments from ybuf (own-wave rows, no barrier needed vs ybuf)
  bh8 a2[2][4];
#pragma unroll
  for (int rt = 0; rt < 2; ++rt)
#pragma unroll
    for (int kk = 0; kk < 4; ++kk)
      a2[rt][kk] = *reinterpret_cast<const bh8*>(
          &ybuf[(wid * 32 + rt * 16 + lr) * WPAD + kk * 32 + 8 * lg]);

  __syncthreads();           // W2T staged

  // GEMM2 + bias + relu -> ybuf (z), accumulate BN stats
#pragma unroll
  for (int n0 = 0; n0 < 8; ++n0) {
    fl4 acc[2] = {{0,0,0,0},{0,0,0,0}};
#pragma unroll
    for (int kk = 0; kk < 4; ++kk) {
      bh8 b = *reinterpret_cast<const bh8*>(&wbuf[(n0 * 16 + lr) * WPAD + kk * 32 + 8 * lg]);
      acc[0] = __builtin_amdgcn_mfma_f32_16x16x32_bf16(a2[0][kk], b, acc[0], 0, 0, 0);
      acc[1] = __builtin_amdgcn_mfma_f32_16x16x32_bf16(a2[1][kk], b, acc[1], 0, 0, 0);
    }
    float bias = b2[n0 * 16 + lr];
    float sp = 0.f, qp = 0.f;
#pragma unroll
    for (int rt = 0; rt < 2; ++rt)
#pragma unroll
      for (int r = 0; r < 4; ++r) {
        int row = row0 + wid * 32 + rt * 16 + 4 * lg + r;
        float v = acc[rt][r] + bias;
        v = v > 0.f ? v : 0.f;
        ybuf[(wid * 32 + rt * 16 + 4 * lg + r) * WPAD + n0 * 16 + lr] = f2bfbits(v);
        if (row < N_NODES) { sp += v; qp += v * v; }
      }
    sp += __shfl_xor(sp, 16); sp += __shfl_xor(sp, 32);
    qp += __shfl_xor(qp, 16); qp += __shfl_xor(qp, 32);
    if (lg == 0) { red[wid][0][n0 * 16 + lr] = sp; red[wid][1][n0 * 16 + lr] = qp; }
  }

  __syncthreads();

  {
    int which = tid >> 7, c = tid & 127;
    float v = red[0][which][c] + red[1][which][c] + red[2][which][c] + red[3][which][c];
    unsafeAtomicAdd(&stats[which * 128 + c], v);
  }

  // coalesced z store
#pragma unroll
  for (int i = 0; i < 8; ++i) {
    int chunk = tid + i * 256;
    int r = chunk >> 4, c8 = (chunk & 15) << 3;
    int row = row0 + r;
    if (row < N_NODES)
      *reinterpret_cast<uint4*>(&Z[(long)row * DIM_H + c8]) =
          *reinterpret_cast<const uint4*>(&ybuf[r * WPAD + c8]);
  }
}

// ---------------- BN finalize: s = gamma*rsqrt(var+eps), b = beta - mean*s ----------------
__global__ void bn_finalize(const float* __restrict__ stats, const float* __restrict__ gamma,
                            const float* __restrict__ beta, float* __restrict__ sb) {
  int c = threadIdx.x;
  const float inv_n = 1.0f / (float)N_NODES;
  float mean = stats[c] * inv_n;
  float var  = stats[128 + c] * inv_n - mean * mean;
  float s = gamma[c] * rsqrtf(var + BN_EPS);
  sb[c] = s;
  sb[128 + c] = beta[c] - mean * s;
}

// ---------------- head: BN-affine -> fc1 -> relu -> dropout -> fc2 -> log_softmax ----------------
__global__ __launch_bounds__(256, 2)
void head_kernel(const unsigned short* __restrict__ Z, const float* __restrict__ sb,
                 const unsigned short* __restrict__ F1T, const float* __restrict__ fc1b,
                 const unsigned short* __restrict__ F2T, const float* __restrict__ fc2b,
                 const float* __restrict__ mask, float* __restrict__ out) {
  __shared__ __align__(16) unsigned short wbuf[128 * WPAD];
  __shared__ __align__(16) unsigned short ybuf[128 * WPAD];

  const int tid = threadIdx.x;
  const int wid = tid >> 6, lane = tid & 63;
  const int lr = lane & 15, lg = lane >> 4;
  const int row0 = blockIdx.x * 128;

  // stage FC1T
#pragma unroll
  for (int i = 0; i < 8; ++i) {
    int chunk = tid + i * 256;
    int r = chunk >> 4, c8 = (chunk & 15) << 3;
    *reinterpret_cast<uint4*>(&wbuf[r * WPAD + c8]) =
        *reinterpret_cast<const uint4*>(&F1T[r * 128 + c8]);
  }

  // A fragments: affine(z) in bf16
  bh8 afrag[2][4];
#pragma unroll
  for (int rt = 0; rt < 2; ++rt) {
    int row = row0 + wid * 32 + rt * 16 + lr;
    bool valid = row < N_NODES;
#pragma unroll
    for (int kk = 0; kk < 4; ++kk) {
      int k0 = kk * 32 + 8 * lg;
      us8 t = (us8)0;
      if (valid) {
        us8 zv = *reinterpret_cast<const us8*>(Z + (long)row * DIM_H + k0);
        fl4 s0 = *reinterpret_cast<const fl4*>(sb + k0);
        fl4 s1 = *reinterpret_cast<const fl4*>(sb + k0 + 4);
        fl4 bb0 = *reinterpret_cast<const fl4*>(sb + 128 + k0);
        fl4 bb1 = *reinterpret_cast<const fl4*>(sb + 128 + k0 + 4);
#pragma unroll
        for (int j = 0; j < 4; ++j) {
          t[j]     = f2bfbits(bf2f(zv[j])     * s0[j] + bb0[j]);
          t[4 + j] = f2bfbits(bf2f(zv[4 + j]) * s1[j] + bb1[j]);
        }
      }
      afrag[rt][kk] = __builtin_bit_cast(bh8, t);
    }
  }

  __syncthreads();

  // GEMM1 + fc1b + relu + dropout -> ybuf
#pragma unroll
  for (int n0 = 0; n0 < 8; ++n0) {
    fl4 acc[2] = {{0,0,0,0},{0,0,0,0}};
#pragma unroll
    for (int kk = 0; kk < 4; ++kk) {
      bh8 b = *reinterpret_cast<const bh8*>(&wbuf[(n0 * 16 + lr) * WPAD + kk * 32 + 8 * lg]);
      acc[0] = __builtin_amdgcn_mfma_f32_16x16x32_bf16(afrag[0][kk], b, acc[0], 0, 0, 0);
      acc[1] = __builtin_amdgcn_mfma_f32_16x16x32_bf16(afrag[1][kk], b, acc[1], 0, 0, 0);
    }
    float bias = fc1b[n0 * 16 + lr];
#pragma unroll
    for (int rt = 0; rt < 2; ++rt)
#pragma unroll
      for (int r = 0; r < 4; ++r) {
        int row = row0 + wid * 32 + rt * 16 + 4 * lg + r;
        float v = acc[rt][r] + bias;
        v = v > 0.f ? v : 0.f;
        float mk = (row < N_NODES) ? mask[(long)row * DIM_H + n0 * 16 + lr] : 0.f;
        ybuf[(wid * 32 + rt * 16 + 4 * lg + r) * WPAD + n0 * 16 + lr] = f2bfbits(v * mk);
      }
  }

  __syncthreads();

  // stage FC2T (64 rows)
#pragma unroll
  for (int i = 0; i < 4; ++i) {
    int chunk = tid + i * 256;
    int r = chunk >> 4, c8 = (chunk & 15) << 3;
    *reinterpret_cast<uint4*>(&wbuf[r * WPAD + c8]) =
        *reinterpret_cast<const uint4*>(&F2T[r * 128 + c8]);
  }

  bh8 a2[2][4];
#pragma unroll
  for (int rt = 0; rt < 2; ++rt)
#pragma unroll
    for (int kk = 0; kk < 4; ++kk)
      a2[rt][kk] = *reinterpret_cast<const bh8*>(
          &ybuf[(wid * 32 + rt * 16 + lr) * WPAD + kk * 32 + 8 * lg]);

  __syncthreads();

  // GEMM2 (N=64)
  fl4 acc2[2][4];
#pragma unroll
  for (int n0 = 0; n0 < 4; ++n0) {
    acc2[0][n0] = (fl4){0,0,0,0};
    acc2[1][n0] = (fl4){0,0,0,0};
#pragma unroll
    for (int kk = 0; kk < 4; ++kk) {
      bh8 b = *reinterpret_cast<const bh8*>(&wbuf[(n0 * 16 + lr) * WPAD + kk * 32 + 8 * lg]);
      acc2[0][n0] = __builtin_amdgcn_mfma_f32_16x16x32_bf16(a2[0][kk], b, acc2[0][n0], 0, 0, 0);
      acc2[1][n0] = __builtin_amdgcn_mfma_f32_16x16x32_bf16(a2[1][kk], b, acc2[1][n0], 0, 0, 0);
    }
    float bias = fc2b[n0 * 16 + lr];
#pragma unroll
    for (int rt = 0; rt < 2; ++rt)
#pragma unroll
      for (int r = 0; r < 4; ++r) acc2[rt][n0][r] += bias;
  }

  // log_softmax over 64 cols (in-lane 4 × 16 lanes of the group) + store
#pragma unroll
  for (int rt = 0; rt < 2; ++rt) {
#pragma unroll
    for (int r = 0; r < 4; ++r) {
      float m = fmaxf(fmaxf(acc2[rt][0][r], acc2[rt][1][r]),
                      fmaxf(acc2[rt][2][r], acc2[rt][3][r]));
#pragma unroll
      for (int d = 1; d < 16; d <<= 1) m = fmaxf(m, __shfl_xor(m, d, 16));
      float se = 0.f;
#pragma unroll
      for (int n0 = 0; n0 < 4; ++n0) se += __expf(acc2[rt][n0][r] - m);
#pragma unroll
      for (int d = 1; d < 16; d <<= 1) se += __shfl_xor(se, d, 16);
      float lse = m + __logf(se);
      int row = row0 + wid * 32 + rt * 16 + 4 * lg + r;
      if (row < N_NODES) {
#pragma unroll
        for (int n0 = 0; n0 < 4; ++n0)
          out[(long)row * DIM_OUT + n0 * 16 + lr] = acc2[rt][n0][r] - lse;
      }
    }
  }
}

// ---------------- launcher ----------------
extern "C" void kernel_launch(void* const* d_in, const int* in_sizes, int n_in,
                              void* d_out, int out_size, void* d_ws, size_t ws_size,
                              hipStream_t stream) {
  const float* x      = (const float*)d_in[0];
  const int*   ei     = (const int*)d_in[1];
  const float* cw1    = (const float*)d_in[2];
  const float* cb1    = (const float*)d_in[3];
  const float* cw2    = (const float*)d_in[4];
  const float* cb2    = (const float*)d_in[5];
  const float* gamma  = (const float*)d_in[6];
  const float* beta   = (const float*)d_in[7];
  const float* fc1w   = (const float*)d_in[8];
  const float* fc1b   = (const float*)d_in[9];
  const float* fc2w   = (const float*)d_in[10];
  const float* fc2b   = (const float*)d_in[11];
  const float* mask   = (const float*)d_in[12];
  float* out = (float*)d_out;

  char* ws = (char*)d_ws;
  float*          agg   = (float*)ws;                          // 51,200,000 B
  unsigned short* Zb    = (unsigned short*)(ws + 51200000);    // 25,600,000 B
  unsigned short* W1T   = (unsigned short*)(ws + 76800000);    //     98,304 B
  unsigned short* W2T   = (unsigned short*)(ws + 76898304);    //     98,304 B
  unsigned short* F1T   = (unsigned short*)(ws + 76996608);    //     32,768 B
  unsigned short* F2T   = (unsigned short*)(ws + 77029376);    //     16,384 B
  float*          stats = (float*)(ws + 77045760);             //      3,072 B
  float*          sb    = (float*)(ws + 77048832);             //      3,072 B
  if (ws_size < 77051904) return;

  prep_kernel<<<192, 256, 0, stream>>>(cw1, cw2, fc1w, fc2w, W1T, W2T, F1T, F2T, stats);

  // layer 0 (h = x, fp32)
  agg_init_x<<<12500, 256, 0, stream>>>(x, agg);
  scatter_x<<<75000, 256, 0, stream>>>(x, ei, agg);
  mlp_kernel<<<782, 256, 0, stream>>>(agg, W1T, cb1, W2T, cb2, Zb, stats);
  bn_finalize<<<1, 128, 0, stream>>>(stats, gamma, beta, sb);

  // layer 1
  agg_init_z<<<6250, 256, 0, stream>>>(Zb, sb, agg);
  scatter_z<<<75000, 256, 0, stream>>>(Zb, sb, ei, agg);
  mlp_kernel<<<782, 256, 0, stream>>>(agg, W1T + 16384, cb1 + 128, W2T + 16384, cb2 + 128,
                                      Zb, stats + 256);
  bn_finalize<<<1, 128, 0, stream>>>(stats + 256, gamma + 128, beta + 128, sb + 256);

  // layer 2
  agg_init_z<<<6250, 256, 0, stream>>>(Zb, sb + 256, agg);
  scatter_z<<<75000, 256, 0, stream>>>(Zb, sb + 256, ei, agg);
  mlp_kernel<<<782, 256, 0, stream>>>(agg, W1T + 32768, cb1 + 256, W2T + 32768, cb2 + 256,
                                      Zb, stats + 512);
  bn_finalize<<<1, 128, 0, stream>>>(stats + 512, gamma + 256, beta + 256, sb + 512);

  // head
  head_kernel<<<782, 256, 0, stream>>>(Zb, sb + 512, F1T, fc1b, F2T, fc2b, mask, out);
}

// Round 3
// 380.547 us; speedup vs baseline: 8.5044x; 8.5044x over previous
//
#include <hip/hip_runtime.h>
#include <stdint.h>

#define N_NODES 100000
#define N_EDGES 600000
#define DIM_H   128
#define DIM_OUT 64
#define WPAD    136      // padded LDS row stride in ushort units
#define BN_EPS  1e-5f
#define NBLK    391      // ceil(N_NODES/256)

typedef __attribute__((ext_vector_type(8))) __bf16        bh8;
typedef __attribute__((ext_vector_type(2))) float         fl2;
typedef __attribute__((ext_vector_type(4))) float         fl4;
typedef __attribute__((ext_vector_type(8))) unsigned short us8;

__device__ __forceinline__ unsigned short f2bfbits(float f) {
  unsigned int u = __builtin_bit_cast(unsigned int, f);
  u += 0x7fffu + ((u >> 16) & 1u);           // RNE
  return (unsigned short)(u >> 16);
}
__device__ __forceinline__ float bf2f(unsigned short b) {
  unsigned int u = ((unsigned int)b) << 16;
  return __builtin_bit_cast(float, u);
}

// ---------------- weight prep: transpose + bf16 cast, zero stats ----------------
__global__ void prep_kernel(const float* __restrict__ cw1, const float* __restrict__ cw2,
                            const float* __restrict__ fc1w, const float* __restrict__ fc2w,
                            unsigned short* __restrict__ W1T, unsigned short* __restrict__ W2T,
                            unsigned short* __restrict__ F1T, unsigned short* __restrict__ F2T,
                            float* __restrict__ stats) {
  int t = blockIdx.x * 256 + threadIdx.x;
  if (t < 3 * 16384) {
    int l = t / 16384, r = t % 16384;
    int nn = r >> 7, k = r & 127;            // W*T[l][n][k] = W[l][k][n]
    W1T[t] = f2bfbits(cw1[l * 16384 + k * 128 + nn]);
    W2T[t] = f2bfbits(cw2[l * 16384 + k * 128 + nn]);
  }
  if (t < 16384) { int nn = t >> 7, k = t & 127; F1T[t] = f2bfbits(fc1w[k * 128 + nn]); }
  if (t < 8192)  { int nn = t >> 7, k = t & 127; F2T[t] = f2bfbits(fc2w[k * 64 + nn]); }
  if (t < 768)   stats[t] = 0.f;
}

// ---------------- CSR build ----------------
__global__ void deg_zero(int* __restrict__ deg) {
  int i = blockIdx.x * 256 + threadIdx.x;
  if (i < N_NODES) deg[i] = 0;
}

__global__ void deg_count(const int* __restrict__ ei, int* __restrict__ deg) {
  int e = blockIdx.x * 256 + threadIdx.x;
  if (e < N_EDGES) atomicAdd(&deg[ei[N_EDGES + e]], 1);
}

// block-level exclusive scan (256/block); rowstart = local excl, bsum[b] = block total
__global__ void scanA(const int* __restrict__ deg, int* __restrict__ rowstart,
                      int* __restrict__ bsum) {
  __shared__ int s[256];
  int t = threadIdx.x, i = blockIdx.x * 256 + t;
  int v = (i < N_NODES) ? deg[i] : 0;
  s[t] = v;
  __syncthreads();
#pragma unroll
  for (int off = 1; off < 256; off <<= 1) {
    int u = (t >= off) ? s[t - off] : 0;
    __syncthreads();
    s[t] += u;
    __syncthreads();
  }
  if (i < N_NODES) rowstart[i] = s[t] - v;
  if (t == 0) bsum[blockIdx.x] = s[255];
}

__global__ void scanB(const int* __restrict__ bsum, int* __restrict__ boff) {
  __shared__ int s[512];
  int t = threadIdx.x;
  int v = (t < NBLK) ? bsum[t] : 0;
  s[t] = v;
  __syncthreads();
#pragma unroll
  for (int off = 1; off < 512; off <<= 1) {
    int u = (t >= off) ? s[t - off] : 0;
    __syncthreads();
    s[t] += u;
    __syncthreads();
  }
  if (t < NBLK) boff[t] = s[t] - v;   // exclusive
}

__global__ void scanC(int* __restrict__ rowstart, const int* __restrict__ boff,
                      int* __restrict__ cursor) {
  int i = blockIdx.x * 256 + threadIdx.x;
  if (i < N_NODES) {
    int v = rowstart[i] + boff[i >> 8];
    rowstart[i] = v;
    cursor[i] = v;
  }
  if (i == 0) rowstart[N_NODES] = N_EDGES;
}

__global__ void csr_fill(const int* __restrict__ ei, int* __restrict__ cursor,
                         int* __restrict__ csr_src) {
  int e = blockIdx.x * 256 + threadIdx.x;
  if (e < N_EDGES) {
    int pos = atomicAdd(&cursor[ei[N_EDGES + e]], 1);
    csr_src[pos] = ei[e];
  }
}

// ---------------- gather: agg_bf16[i] = h[i] + sum_{j in N(i)} h[j] ----------------
__global__ __launch_bounds__(256)
void gather_x(const float* __restrict__ x, const int* __restrict__ rowstart,
              const int* __restrict__ csr, unsigned short* __restrict__ aggB) {
  int node = blockIdx.x * 4 + (threadIdx.x >> 6);
  int lane = threadIdx.x & 63;
  int c = lane * 2;
  int rs = rowstart[node], re = rowstart[node + 1];
  fl2 a = *reinterpret_cast<const fl2*>(x + (long)node * DIM_H + c);
  int j = rs;
  for (; j + 1 < re; j += 2) {
    int s0 = csr[j], s1 = csr[j + 1];
    fl2 p = *reinterpret_cast<const fl2*>(x + (long)s0 * DIM_H + c);
    fl2 q = *reinterpret_cast<const fl2*>(x + (long)s1 * DIM_H + c);
    a.x += p.x + q.x; a.y += p.y + q.y;
  }
  if (j < re) {
    int s0 = csr[j];
    fl2 p = *reinterpret_cast<const fl2*>(x + (long)s0 * DIM_H + c);
    a.x += p.x; a.y += p.y;
  }
  unsigned int pk = ((unsigned int)f2bfbits(a.y) << 16) | f2bfbits(a.x);
  *reinterpret_cast<unsigned int*>(aggB + (long)node * DIM_H + c) = pk;
}

// agg_bf16[i] = sum over {i}∪N(i) of (s*z_j + b)  =  s*sum(z_j) + cnt*b
__global__ __launch_bounds__(256)
void gather_z(const unsigned short* __restrict__ Z, const float* __restrict__ sb,
              const int* __restrict__ rowstart, const int* __restrict__ csr,
              unsigned short* __restrict__ aggB) {
  int node = blockIdx.x * 4 + (threadIdx.x >> 6);
  int lane = threadIdx.x & 63;
  int c = lane * 2;
  int rs = rowstart[node], re = rowstart[node + 1];
  float sc0 = sb[c], sc1 = sb[c + 1], bc0 = sb[128 + c], bc1 = sb[128 + c + 1];
  unsigned int zv = *reinterpret_cast<const unsigned int*>(Z + (long)node * DIM_H + c);
  float a0 = bf2f((unsigned short)zv), a1 = bf2f((unsigned short)(zv >> 16));
  int j = rs;
  for (; j + 1 < re; j += 2) {
    int s0 = csr[j], s1 = csr[j + 1];
    unsigned int p = *reinterpret_cast<const unsigned int*>(Z + (long)s0 * DIM_H + c);
    unsigned int q = *reinterpret_cast<const unsigned int*>(Z + (long)s1 * DIM_H + c);
    a0 += bf2f((unsigned short)p) + bf2f((unsigned short)q);
    a1 += bf2f((unsigned short)(p >> 16)) + bf2f((unsigned short)(q >> 16));
  }
  if (j < re) {
    int s0 = csr[j];
    unsigned int p = *reinterpret_cast<const unsigned int*>(Z + (long)s0 * DIM_H + c);
    a0 += bf2f((unsigned short)p);
    a1 += bf2f((unsigned short)(p >> 16));
  }
  float cnt = (float)(re - rs + 1);
  float o0 = sc0 * a0 + cnt * bc0;
  float o1 = sc1 * a1 + cnt * bc1;
  unsigned int pk = ((unsigned int)f2bfbits(o1) << 16) | f2bfbits(o0);
  *reinterpret_cast<unsigned int*>(aggB + (long)node * DIM_H + c) = pk;
}

// ---------------- fused GIN MLP: z = relu(relu(agg@W1+b1)@W2+b2), + BN stats ----------------
__global__ __launch_bounds__(256, 2)
void mlp_kernel(const unsigned short* __restrict__ A,
                const unsigned short* __restrict__ W1T, const float* __restrict__ b1,
                const unsigned short* __restrict__ W2T, const float* __restrict__ b2,
                unsigned short* __restrict__ Z, float* __restrict__ stats) {
  __shared__ __align__(16) unsigned short wbuf[128 * WPAD];
  __shared__ __align__(16) unsigned short ybuf[128 * WPAD];
  __shared__ float red[4][2][128];

  const int tid = threadIdx.x;
  const int wid = tid >> 6, lane = tid & 63;
  const int lr = lane & 15, lg = lane >> 4;
  const int row0 = blockIdx.x * 128;

  // stage W1T
#pragma unroll
  for (int i = 0; i < 8; ++i) {
    int chunk = tid + i * 256;
    int r = chunk >> 4, c8 = (chunk & 15) << 3;
    *reinterpret_cast<uint4*>(&wbuf[r * WPAD + c8]) =
        *reinterpret_cast<const uint4*>(&W1T[r * 128 + c8]);
  }

  // A fragments straight from bf16 global
  bh8 afrag[2][4];
#pragma unroll
  for (int rt = 0; rt < 2; ++rt) {
    int row = row0 + wid * 32 + rt * 16 + lr;
    bool valid = row < N_NODES;
    const unsigned short* ap = A + (long)row * DIM_H;
#pragma unroll
    for (int kk = 0; kk < 4; ++kk) {
      us8 t = (us8)0;
      if (valid) t = *reinterpret_cast<const us8*>(ap + kk * 32 + 8 * lg);
      afrag[rt][kk] = __builtin_bit_cast(bh8, t);
    }
  }

  __syncthreads();

  // GEMM1 + bias + relu -> ybuf (bf16)
#pragma unroll
  for (int n0 = 0; n0 < 8; ++n0) {
    fl4 acc[2] = {{0,0,0,0},{0,0,0,0}};
#pragma unroll
    for (int kk = 0; kk < 4; ++kk) {
      bh8 b = *reinterpret_cast<const bh8*>(&wbuf[(n0 * 16 + lr) * WPAD + kk * 32 + 8 * lg]);
      acc[0] = __builtin_amdgcn_mfma_f32_16x16x32_bf16(afrag[0][kk], b, acc[0], 0, 0, 0);
      acc[1] = __builtin_amdgcn_mfma_f32_16x16x32_bf16(afrag[1][kk], b, acc[1], 0, 0, 0);
    }
    float bias = b1[n0 * 16 + lr];
#pragma unroll
    for (int rt = 0; rt < 2; ++rt)
#pragma unroll
      for (int r = 0; r < 4; ++r) {
        float v = acc[rt][r] + bias;
        v = v > 0.f ? v : 0.f;
        ybuf[(wid * 32 + rt * 16 + 4 * lg + r) * WPAD + n0 * 16 + lr] = f2bfbits(v);
      }
  }

  __syncthreads();           // everyone done with W1T + Y1 writes

  // stage W2T over wbuf
#pragma unroll
  for (int i = 0; i < 8; ++i) {
    int chunk = tid + i * 256;
    int r = chunk >> 4, c8 = (chunk & 15) << 3;
    *reinterpret_cast<uint4*>(&wbuf[r * WPAD + c8]) =
        *reinterpret_cast<const uint4*>(&W2T[r * 128 + c8]);
  }

  // A2 fragments from ybuf (own-wave rows)
  bh8 a2[2][4];
#pragma unroll
  for (int rt = 0; rt < 2; ++rt)
#pragma unroll
    for (int kk = 0; kk < 4; ++kk)
      a2[rt][kk] = *reinterpret_cast<const bh8*>(
          &ybuf[(wid * 32 + rt * 16 + lr) * WPAD + kk * 32 + 8 * lg]);

  __syncthreads();           // W2T staged

  // GEMM2 + bias + relu -> ybuf (z), accumulate BN stats
#pragma unroll
  for (int n0 = 0; n0 < 8; ++n0) {
    fl4 acc[2] = {{0,0,0,0},{0,0,0,0}};
#pragma unroll
    for (int kk = 0; kk < 4; ++kk) {
      bh8 b = *reinterpret_cast<const bh8*>(&wbuf[(n0 * 16 + lr) * WPAD + kk * 32 + 8 * lg]);
      acc[0] = __builtin_amdgcn_mfma_f32_16x16x32_bf16(a2[0][kk], b, acc[0], 0, 0, 0);
      acc[1] = __builtin_amdgcn_mfma_f32_16x16x32_bf16(a2[1][kk], b, acc[1], 0, 0, 0);
    }
    float bias = b2[n0 * 16 + lr];
    float sp = 0.f, qp = 0.f;
#pragma unroll
    for (int rt = 0; rt < 2; ++rt)
#pragma unroll
      for (int r = 0; r < 4; ++r) {
        int row = row0 + wid * 32 + rt * 16 + 4 * lg + r;
        float v = acc[rt][r] + bias;
        v = v > 0.f ? v : 0.f;
        ybuf[(wid * 32 + rt * 16 + 4 * lg + r) * WPAD + n0 * 16 + lr] = f2bfbits(v);
        if (row < N_NODES) { sp += v; qp += v * v; }
      }
    sp += __shfl_xor(sp, 16); sp += __shfl_xor(sp, 32);
    qp += __shfl_xor(qp, 16); qp += __shfl_xor(qp, 32);
    if (lg == 0) { red[wid][0][n0 * 16 + lr] = sp; red[wid][1][n0 * 16 + lr] = qp; }
  }

  __syncthreads();

  {
    int which = tid >> 7, c = tid & 127;
    float v = red[0][which][c] + red[1][which][c] + red[2][which][c] + red[3][which][c];
    unsafeAtomicAdd(&stats[which * 128 + c], v);
  }

  // coalesced z store
#pragma unroll
  for (int i = 0; i < 8; ++i) {
    int chunk = tid + i * 256;
    int r = chunk >> 4, c8 = (chunk & 15) << 3;
    int row = row0 + r;
    if (row < N_NODES)
      *reinterpret_cast<uint4*>(&Z[(long)row * DIM_H + c8]) =
          *reinterpret_cast<const uint4*>(&ybuf[r * WPAD + c8]);
  }
}

// ---------------- BN finalize: s = gamma*rsqrt(var+eps), b = beta - mean*s ----------------
__global__ void bn_finalize(const float* __restrict__ stats, const float* __restrict__ gamma,
                            const float* __restrict__ beta, float* __restrict__ sb) {
  int c = threadIdx.x;
  const float inv_n = 1.0f / (float)N_NODES;
  float mean = stats[c] * inv_n;
  float var  = stats[128 + c] * inv_n - mean * mean;
  float s = gamma[c] * rsqrtf(var + BN_EPS);
  sb[c] = s;
  sb[128 + c] = beta[c] - mean * s;
}

// ---------------- head: BN-affine -> fc1 -> relu -> dropout -> fc2 -> log_softmax ----------------
__global__ __launch_bounds__(256, 2)
void head_kernel(const unsigned short* __restrict__ Z, const float* __restrict__ sb,
                 const unsigned short* __restrict__ F1T, const float* __restrict__ fc1b,
                 const unsigned short* __restrict__ F2T, const float* __restrict__ fc2b,
                 const float* __restrict__ mask, float* __restrict__ out) {
  __shared__ __align__(16) unsigned short wbuf[128 * WPAD];
  __shared__ __align__(16) unsigned short ybuf[128 * WPAD];

  const int tid = threadIdx.x;
  const int wid = tid >> 6, lane = tid & 63;
  const int lr = lane & 15, lg = lane >> 4;
  const int row0 = blockIdx.x * 128;

  // stage FC1T
#pragma unroll
  for (int i = 0; i < 8; ++i) {
    int chunk = tid + i * 256;
    int r = chunk >> 4, c8 = (chunk & 15) << 3;
    *reinterpret_cast<uint4*>(&wbuf[r * WPAD + c8]) =
        *reinterpret_cast<const uint4*>(&F1T[r * 128 + c8]);
  }

  // A fragments: affine(z) in bf16
  bh8 afrag[2][4];
#pragma unroll
  for (int rt = 0; rt < 2; ++rt) {
    int row = row0 + wid * 32 + rt * 16 + lr;
    bool valid = row < N_NODES;
#pragma unroll
    for (int kk = 0; kk < 4; ++kk) {
      int k0 = kk * 32 + 8 * lg;
      us8 t = (us8)0;
      if (valid) {
        us8 zv = *reinterpret_cast<const us8*>(Z + (long)row * DIM_H + k0);
        fl4 s0 = *reinterpret_cast<const fl4*>(sb + k0);
        fl4 s1 = *reinterpret_cast<const fl4*>(sb + k0 + 4);
        fl4 bb0 = *reinterpret_cast<const fl4*>(sb + 128 + k0);
        fl4 bb1 = *reinterpret_cast<const fl4*>(sb + 128 + k0 + 4);
#pragma unroll
        for (int j = 0; j < 4; ++j) {
          t[j]     = f2bfbits(bf2f(zv[j])     * s0[j] + bb0[j]);
          t[4 + j] = f2bfbits(bf2f(zv[4 + j]) * s1[j] + bb1[j]);
        }
      }
      afrag[rt][kk] = __builtin_bit_cast(bh8, t);
    }
  }

  __syncthreads();

  // GEMM1 + fc1b + relu + dropout -> ybuf
#pragma unroll
  for (int n0 = 0; n0 < 8; ++n0) {
    fl4 acc[2] = {{0,0,0,0},{0,0,0,0}};
#pragma unroll
    for (int kk = 0; kk < 4; ++kk) {
      bh8 b = *reinterpret_cast<const bh8*>(&wbuf[(n0 * 16 + lr) * WPAD + kk * 32 + 8 * lg]);
      acc[0] = __builtin_amdgcn_mfma_f32_16x16x32_bf16(afrag[0][kk], b, acc[0], 0, 0, 0);
      acc[1] = __builtin_amdgcn_mfma_f32_16x16x32_bf16(afrag[1][kk], b, acc[1], 0, 0, 0);
    }
    float bias = fc1b[n0 * 16 + lr];
#pragma unroll
    for (int rt = 0; rt < 2; ++rt)
#pragma unroll
      for (int r = 0; r < 4; ++r) {
        int row = row0 + wid * 32 + rt * 16 + 4 * lg + r;
        float v = acc[rt][r] + bias;
        v = v > 0.f ? v : 0.f;
        float mk = (row < N_NODES) ? mask[(long)row * DIM_H + n0 * 16 + lr] : 0.f;
        ybuf[(wid * 32 + rt * 16 + 4 * lg + r) * WPAD + n0 * 16 + lr] = f2bfbits(v * mk);
      }
  }

  __syncthreads();

  // stage FC2T (64 rows)
#pragma unroll
  for (int i = 0; i < 4; ++i) {
    int chunk = tid + i * 256;
    int r = chunk >> 4, c8 = (chunk & 15) << 3;
    *reinterpret_cast<uint4*>(&wbuf[r * WPAD + c8]) =
        *reinterpret_cast<const uint4*>(&F2T[r * 128 + c8]);
  }

  bh8 a2[2][4];
#pragma unroll
  for (int rt = 0; rt < 2; ++rt)
#pragma unroll
    for (int kk = 0; kk < 4; ++kk)
      a2[rt][kk] = *reinterpret_cast<const bh8*>(
          &ybuf[(wid * 32 + rt * 16 + lr) * WPAD + kk * 32 + 8 * lg]);

  __syncthreads();

  // GEMM2 (N=64)
  fl4 acc2[2][4];
#pragma unroll
  for (int n0 = 0; n0 < 4; ++n0) {
    acc2[0][n0] = (fl4){0,0,0,0};
    acc2[1][n0] = (fl4){0,0,0,0};
#pragma unroll
    for (int kk = 0; kk < 4; ++kk) {
      bh8 b = *reinterpret_cast<const bh8*>(&wbuf[(n0 * 16 + lr) * WPAD + kk * 32 + 8 * lg]);
      acc2[0][n0] = __builtin_amdgcn_mfma_f32_16x16x32_bf16(a2[0][kk], b, acc2[0][n0], 0, 0, 0);
      acc2[1][n0] = __builtin_amdgcn_mfma_f32_16x16x32_bf16(a2[1][kk], b, acc2[1][n0], 0, 0, 0);
    }
    float bias = fc2b[n0 * 16 + lr];
#pragma unroll
    for (int rt = 0; rt < 2; ++rt)
#pragma unroll
      for (int r = 0; r < 4; ++r) acc2[rt][n0][r] += bias;
  }

  // log_softmax over 64 cols + store
#pragma unroll
  for (int rt = 0; rt < 2; ++rt) {
#pragma unroll
    for (int r = 0; r < 4; ++r) {
      float m = fmaxf(fmaxf(acc2[rt][0][r], acc2[rt][1][r]),
                      fmaxf(acc2[rt][2][r], acc2[rt][3][r]));
#pragma unroll
      for (int d = 1; d < 16; d <<= 1) m = fmaxf(m, __shfl_xor(m, d, 16));
      float se = 0.f;
#pragma unroll
      for (int n0 = 0; n0 < 4; ++n0) se += __expf(acc2[rt][n0][r] - m);
#pragma unroll
      for (int d = 1; d < 16; d <<= 1) se += __shfl_xor(se, d, 16);
      float lse = m + __logf(se);
      int row = row0 + wid * 32 + rt * 16 + 4 * lg + r;
      if (row < N_NODES) {
#pragma unroll
        for (int n0 = 0; n0 < 4; ++n0)
          out[(long)row * DIM_OUT + n0 * 16 + lr] = acc2[rt][n0][r] - lse;
      }
    }
  }
}

// ---------------- launcher ----------------
extern "C" void kernel_launch(void* const* d_in, const int* in_sizes, int n_in,
                              void* d_out, int out_size, void* d_ws, size_t ws_size,
                              hipStream_t stream) {
  const float* x      = (const float*)d_in[0];
  const int*   ei     = (const int*)d_in[1];
  const float* cw1    = (const float*)d_in[2];
  const float* cb1    = (const float*)d_in[3];
  const float* cw2    = (const float*)d_in[4];
  const float* cb2    = (const float*)d_in[5];
  const float* gamma  = (const float*)d_in[6];
  const float* beta   = (const float*)d_in[7];
  const float* fc1w   = (const float*)d_in[8];
  const float* fc1b   = (const float*)d_in[9];
  const float* fc2w   = (const float*)d_in[10];
  const float* fc2b   = (const float*)d_in[11];
  const float* mask   = (const float*)d_in[12];
  float* out = (float*)d_out;

  char* ws = (char*)d_ws;
  unsigned short* aggB  = (unsigned short*)ws;                 // 25,600,000 B
  unsigned short* Zb    = (unsigned short*)(ws + 25600000);    // 25,600,000 B
  unsigned short* W1T   = (unsigned short*)(ws + 51200000);    //     98,304 B
  unsigned short* W2T   = (unsigned short*)(ws + 51298304);    //     98,304 B
  unsigned short* F1T   = (unsigned short*)(ws + 51396608);    //     32,768 B
  unsigned short* F2T   = (unsigned short*)(ws + 51429376);    //     16,384 B
  float*          stats = (float*)(ws + 51445760);             //      3,072 B
  float*          sb    = (float*)(ws + 51448832);             //      3,072 B
  int*            rowst = (int*)(ws + 51451904);               //    400,004 B
  int*            cursor= (int*)(ws + 51851908);               //    400,000 B
  int*            csr   = (int*)(ws + 52251908);               //  2,400,000 B
  int*            bsum  = (int*)(ws + 54651908);               //      1,564 B
  int*            boff  = (int*)(ws + 54653472);               //      1,564 B
  if (ws_size < 54655036u) return;

  prep_kernel<<<192, 256, 0, stream>>>(cw1, cw2, fc1w, fc2w, W1T, W2T, F1T, F2T, stats);

  // CSR build (graph is shared by all 3 layers)
  deg_zero<<<NBLK, 256, 0, stream>>>(cursor);                  // cursor doubles as deg
  deg_count<<<2344, 256, 0, stream>>>(ei, cursor);
  scanA<<<NBLK, 256, 0, stream>>>(cursor, rowst, bsum);
  scanB<<<1, 512, 0, stream>>>(bsum, boff);
  scanC<<<NBLK, 256, 0, stream>>>(rowst, boff, cursor);
  csr_fill<<<2344, 256, 0, stream>>>(ei, cursor, csr);

  // layer 0 (h = x, fp32)
  gather_x<<<25000, 256, 0, stream>>>(x, rowst, csr, aggB);
  mlp_kernel<<<782, 256, 0, stream>>>(aggB, W1T, cb1, W2T, cb2, Zb, stats);
  bn_finalize<<<1, 128, 0, stream>>>(stats, gamma, beta, sb);

  // layer 1
  gather_z<<<25000, 256, 0, stream>>>(Zb, sb, rowst, csr, aggB);
  mlp_kernel<<<782, 256, 0, stream>>>(aggB, W1T + 16384, cb1 + 128, W2T + 16384, cb2 + 128,
                                      Zb, stats + 256);
  bn_finalize<<<1, 128, 0, stream>>>(stats + 256, gamma + 128, beta + 128, sb + 256);

  // layer 2
  gather_z<<<25000, 256, 0, stream>>>(Zb, sb + 256, rowst, csr, aggB);
  mlp_kernel<<<782, 256, 0, stream>>>(aggB, W1T + 32768, cb1 + 256, W2T + 32768, cb2 + 256,
                                      Zb, stats + 512);
  bn_finalize<<<1, 128, 0, stream>>>(stats + 512, gamma + 256, beta + 256, sb + 512);

  // head
  head_kernel<<<782, 256, 0, stream>>>(Zb, sb + 512, F1T, fc1b, F2T, fc2b, mask, out);
}